// Round 5
// baseline (194.695 us; speedup 1.0000x reference)
//
#include <hip/hip_runtime.h>

#define CH_EPS 1e-6f
#define NPTS 8192
#define NB 4
#define QPT 8                      // queries per thread
#define QCHUNK (256 * QPT)         // 2048 queries per block
#define NQ_TOT (2 * NB * NPTS)     // 65536 queries (dir, batch, point)
#define BIGF 3.0e38f
#define NFIN 256                   // finalize blocks (last arrivals)

// Fused chamfer: phase 1 = per-segment min scan (NO index tracking -> 3 FMA +
// 0.5 min3 per pair), phase 2 (last NFIN ticket arrivals) = merge segment
// minima, re-scan winning segment for the exact argmin, exact distance +
// normal-consistency, block-reduce, atomicAdd.
template <int NSEG>
__global__ __launch_bounds__(256) void chamfer_fused(
    const float* __restrict__ xyz1, const float* __restrict__ xyz2,
    const float* __restrict__ nxyz1, const float* __restrict__ nxyz2,
    float* __restrict__ part, int* __restrict__ ticket,
    float* __restrict__ out) {
    constexpr int SEGSZ = NPTS / NSEG;
    constexpr int NBLK = (NPTS / QCHUNK) * NSEG * 2 * NB;
    __shared__ float4 sY[SEGSZ];
    __shared__ int s_order;
    __shared__ float red[2][4];

    const int tid = threadIdx.x;
    const int chunk = blockIdx.x;   // query chunk
    const int seg = blockIdx.y;     // segment
    const int db = blockIdx.z;      // dir*4 + batch
    const int dir = db >> 2, b = db & 3;

    const float* Q = dir ? xyz2 : xyz1;
    const float* R = (dir ? xyz1 : xyz2) + ((size_t)b * NPTS + seg * SEGSZ) * 3;

    // stage segment: (x, y, z, h = 0.5*|p|^2). h expression must match the
    // re-scan EXACTLY (explicit fmaf chain -> bit-identical recompute).
    for (int k = tid; k < SEGSZ; k += 256) {
        float a = R[3 * k], c = R[3 * k + 1], e = R[3 * k + 2];
        float h = 0.5f * fmaf(a, a, fmaf(c, c, e * e));
        sY[k] = make_float4(a, c, e, h);
    }

    float m0[QPT], m1[QPT], m2[QPT], bt[QPT];
    const int qi0 = chunk * QCHUNK + tid;
#pragma unroll
    for (int q = 0; q < QPT; ++q) {
        const size_t off = ((size_t)b * NPTS + qi0 + q * 256) * 3;
        m0[q] = -Q[off]; m1[q] = -Q[off + 1]; m2[q] = -Q[off + 2];
        bt[q] = BIGF;
    }
    __syncthreads();

#pragma unroll 2
    for (int j = 0; j < SEGSZ; j += 4) {
        float4 y0 = sY[j];
        float4 y1 = sY[j + 1];
        float4 y2 = sY[j + 2];
        float4 y3 = sY[j + 3];
#pragma unroll
        for (int q = 0; q < QPT; ++q) {
            float t0 = fmaf(m0[q], y0.x, fmaf(m1[q], y0.y, fmaf(m2[q], y0.z, y0.w)));
            float t1 = fmaf(m0[q], y1.x, fmaf(m1[q], y1.y, fmaf(m2[q], y1.z, y1.w)));
            float t2 = fmaf(m0[q], y2.x, fmaf(m1[q], y2.y, fmaf(m2[q], y2.z, y2.w)));
            float t3 = fmaf(m0[q], y3.x, fmaf(m1[q], y3.y, fmaf(m2[q], y3.z, y3.w)));
            bt[q] = fminf(fminf(bt[q], t0), t1);   // -> v_min3_f32
            bt[q] = fminf(fminf(bt[q], t2), t3);   // -> v_min3_f32
        }
    }

    const int qbase = dir * (NB * NPTS) + b * NPTS + qi0;
#pragma unroll
    for (int q = 0; q < QPT; ++q)
        part[(size_t)seg * NQ_TOT + qbase + q * 256] = bt[q];

    // ---- ticket: last NFIN arrivals run the finalize phase ----
    __syncthreads();
    if (tid == 0) {
        __threadfence();
        s_order = __hip_atomic_fetch_add(ticket, 1, __ATOMIC_ACQ_REL,
                                         __HIP_MEMORY_SCOPE_AGENT);
    }
    __syncthreads();
    const int order = s_order;
    if (order < NBLK - NFIN) return;

    if (tid == 0) {
        while (__hip_atomic_load(ticket, __ATOMIC_ACQUIRE,
                                 __HIP_MEMORY_SCOPE_AGENT) < NBLK)
            __builtin_amdgcn_s_sleep(2);
    }
    __syncthreads();
    // per-wave acquire so every wave's caches see the published partials
    (void)__hip_atomic_load(ticket, __ATOMIC_ACQUIRE, __HIP_MEMORY_SCOPE_AGENT);

    // ---- finalize: 256 queries per block, 1 per thread ----
    const int fb = order - (NBLK - NFIN);
    const int q = fb * 256 + tid;                  // 0..65535
    const int fdir = q >> 15;
    const int rem = q & 32767;
    const int fbat = rem >> 13;
    const int i = rem & 8191;

    // merge segment minima; strict < with ascending s keeps earliest segment
    float btg = part[q];
    int bs = 0;
#pragma unroll
    for (int s = 1; s < NSEG; ++s) {
        float v = part[(size_t)s * NQ_TOT + q];
        if (v < btg) { btg = v; bs = s; }
    }

    const float* Qf  = fdir ? xyz2 : xyz1;
    const float* Rf  = fdir ? xyz1 : xyz2;
    const float* NQf = fdir ? nxyz2 : nxyz1;
    const float* NRf = fdir ? nxyz1 : nxyz2;

    const size_t qoff = ((size_t)fbat * NPTS + i) * 3;
    const float x0 = Qf[qoff], x1 = Qf[qoff + 1], x2 = Qf[qoff + 2];
    const float n0 = -x0, n1 = -x1, n2 = -x2;

    // re-scan winning segment: exact argmin (strict <, ascending j)
    const float* Rs = Rf + ((size_t)fbat * NPTS + bs * SEGSZ) * 3;
    float btr = BIGF;
    int bj = 0;
    for (int j = 0; j < SEGSZ; ++j) {
        float a = Rs[3 * j], c = Rs[3 * j + 1], e = Rs[3 * j + 2];
        float h = 0.5f * fmaf(a, a, fmaf(c, c, e * e));
        float t = fmaf(n0, a, fmaf(n1, c, fmaf(n2, e, h)));
        if (t < btr) { btr = t; bj = j; }
    }
    const int bi = bs * SEGSZ + bj;

    const size_t roff = ((size_t)fbat * NPTS + bi) * 3;
    const float y0 = Rf[roff], y1 = Rf[roff + 1], y2 = Rf[roff + 2];
    const float e0 = x0 - y0, e1 = x1 - y1, e2 = x2 - y2;
    float d = e0 * e0 + e1 * e1 + e2 * e2;         // exact squared distance

    const float a0 = NQf[qoff], a1 = NQf[qoff + 1], a2 = NQf[qoff + 2];
    const float c0 = NRf[roff], c1 = NRf[roff + 1], c2 = NRf[roff + 2];
    float na = sqrtf(a0 * a0 + a1 * a1 + a2 * a2);
    float nc = sqrtf(c0 * c0 + c1 * c1 + c2 * c2);
    float cs = (a0 * c0 + a1 * c1 + a2 * c2) /
               (fmaxf(na, CH_EPS) * fmaxf(nc, CH_EPS));
    float cn = 1.0f - fabsf(cs);

    for (int off = 32; off; off >>= 1) {
        d  += __shfl_down(d, off);
        cn += __shfl_down(cn, off);
    }
    const int lane = tid & 63, wv = tid >> 6;
    if (lane == 0) { red[0][wv] = d; red[1][wv] = cn; }
    __syncthreads();
    if (tid == 0) {
        float sd = red[0][0] + red[0][1] + red[0][2] + red[0][3];
        float sc = red[1][0] + red[1][1] + red[1][2] + red[1][3];
        const float inv = 1.0f / (float)(NB * NPTS);   // 1/32768
        atomicAdd(out + 0, sd * inv);
        atomicAdd(out + 1, sc * inv);
    }
}

extern "C" void kernel_launch(void* const* d_in, const int* in_sizes, int n_in,
                              void* d_out, int out_size, void* d_ws, size_t ws_size,
                              hipStream_t stream) {
    const float* xyz1  = (const float*)d_in[0];
    const float* xyz2  = (const float*)d_in[1];
    const float* nxyz1 = (const float*)d_in[2];
    const float* nxyz2 = (const float*)d_in[3];
    float* out = (float*)d_out;

    int* ticket = (int*)d_ws;                       // 256-byte header
    float* part = (float*)((char*)d_ws + 256);

    hipMemsetAsync(d_out, 0, 2 * sizeof(float), stream);
    hipMemsetAsync(d_ws, 0, 256, stream);

    const size_t need32 = 256 + (size_t)32 * NQ_TOT * sizeof(float); // ~8 MB
    if (ws_size >= need32) {
        chamfer_fused<32><<<dim3(NPTS / QCHUNK, 32, 2 * NB), dim3(256), 0, stream>>>(
            xyz1, xyz2, nxyz1, nxyz2, part, ticket, out);
    } else {
        chamfer_fused<16><<<dim3(NPTS / QCHUNK, 16, 2 * NB), dim3(256), 0, stream>>>(
            xyz1, xyz2, nxyz1, nxyz2, part, ticket, out);
    }
}

// Round 6
// 114.780 us; speedup vs baseline: 1.6963x; 1.6963x over previous
//
#include <hip/hip_runtime.h>

#define CH_EPS 1e-6f
#define NPTS 8192
#define NB 4
#define NSEG 32
#define SEGSZ (NPTS / NSEG)        // 256 refs per segment
#define CHSZ 64                    // points per argmin chunk
#define NCH (SEGSZ / CHSZ)         // 4 chunks per segment
#define QPT 8                      // queries per thread
#define QCHUNK (256 * QPT)         // 2048 queries per block
#define NQ_TOT (2 * NB * NPTS)     // 65536 queries (dir, batch, point)
#define BIGF 3.0e38f
#define CHMASK 0xFFFFFF80u         // clear low 7 bits: stuff global chunk id

// Phase 1: per-(query, segment) chunked min scan.
// t = 0.5*|y|^2 - x.y has the same argmin as |x-y|^2 (y-dependent part).
// Hot loop: 3 FMA + 0.5 fmin per pair (NO index tracking). Once per 64-point
// chunk, the chunk min is folded into the global best with its 7-bit global
// chunk id stuffed into the low mantissa bits (keys all distinct ->
// deterministic decode; <=2^-16 relative perturbation on near-ties only;
// finalize recomputes exact distances from the decoded chunk).
__global__ __launch_bounds__(256) void chamfer_partial(
    const float* __restrict__ xyz1, const float* __restrict__ xyz2,
    float* __restrict__ part, float* __restrict__ out) {
    __shared__ float4 sY[SEGSZ];                // 4 KB

    const int tid = threadIdx.x;
    const int chunk = blockIdx.x;               // 0..3 (2048-query chunks)
    const int seg = blockIdx.y;                 // 0..NSEG-1
    const int db = blockIdx.z;                  // 0..7
    const int dir = db >> 2, b = db & 3;

    // fold the output-zeroing into this kernel (saves a memset dispatch);
    // finalize runs in a later dispatch, so stream order guarantees visibility
    if (chunk == 0 && seg == 0 && db == 0 && tid < 2) out[tid] = 0.0f;

    const float* Q = dir ? xyz2 : xyz1;
    const float* R = (dir ? xyz1 : xyz2) + ((size_t)b * NPTS + seg * SEGSZ) * 3;

    // stage segment into LDS: (x, y, z, h = 0.5*|p|^2); SEGSZ == blockDim
    {
        float a = R[3 * tid], c = R[3 * tid + 1], e = R[3 * tid + 2];
        sY[tid] = make_float4(a, c, e, 0.5f * fmaf(a, a, fmaf(c, c, e * e)));
    }

    float m0[QPT], m1[QPT], m2[QPT], bt[QPT];
    const int qi0 = chunk * QCHUNK + tid;
#pragma unroll
    for (int q = 0; q < QPT; ++q) {
        const size_t off = ((size_t)b * NPTS + qi0 + q * 256) * 3;
        m0[q] = -Q[off]; m1[q] = -Q[off + 1]; m2[q] = -Q[off + 2];
        bt[q] = BIGF;
    }
    __syncthreads();

    const unsigned gc0 = seg * NCH;             // global chunk id base (uniform)
#pragma unroll
    for (int cc = 0; cc < NCH; ++cc) {
        float cm[QPT];
#pragma unroll
        for (int q = 0; q < QPT; ++q) cm[q] = BIGF;
        const int jb = cc * CHSZ;
        for (int j = jb; j < jb + CHSZ; j += 4) {
            float4 y0 = sY[j];
            float4 y1 = sY[j + 1];
            float4 y2 = sY[j + 2];
            float4 y3 = sY[j + 3];
#pragma unroll
            for (int q = 0; q < QPT; ++q) {
                float t0 = fmaf(m0[q], y0.x, fmaf(m1[q], y0.y, fmaf(m2[q], y0.z, y0.w)));
                float t1 = fmaf(m0[q], y1.x, fmaf(m1[q], y1.y, fmaf(m2[q], y1.z, y1.w)));
                float t2 = fmaf(m0[q], y2.x, fmaf(m1[q], y2.y, fmaf(m2[q], y2.z, y2.w)));
                float t3 = fmaf(m0[q], y3.x, fmaf(m1[q], y3.y, fmaf(m2[q], y3.z, y3.w)));
                cm[q] = fminf(fminf(cm[q], t0), t1);   // -> v_min3_f32
                cm[q] = fminf(fminf(cm[q], t2), t3);   // -> v_min3_f32
            }
        }
        const unsigned gc = gc0 + cc;
#pragma unroll
        for (int q = 0; q < QPT; ++q) {
            float k = __uint_as_float((__float_as_uint(cm[q]) & CHMASK) | gc);
            bt[q] = fminf(bt[q], k);
        }
    }

    const size_t pbase = (size_t)seg * NQ_TOT +
                         (size_t)(dir * (NB * NPTS) + b * NPTS + qi0);
#pragma unroll
    for (int q = 0; q < QPT; ++q) part[pbase + q * 256] = bt[q];
}

// Phase 2: merge NSEG keyed segment minima (coalesced, pure fminf), decode
// the winning 64-point chunk, re-scan it for the exact argmin, exact
// distance + normal-consistency term, block-reduce, atomicAdd.
__global__ __launch_bounds__(256) void finalize_kernel(
    const float* __restrict__ xyz1, const float* __restrict__ xyz2,
    const float* __restrict__ nxyz1, const float* __restrict__ nxyz2,
    const float* __restrict__ part, float* __restrict__ out) {
    __shared__ float red[2][4];

    const int tid = threadIdx.x;
    const int q = blockIdx.x * 256 + tid;       // 0..65535
    const int dir = q >> 15;
    const int rem = q & 32767;
    const int b = rem >> 13;
    const int i = rem & 8191;

    float bt = part[q];
#pragma unroll
    for (int s = 1; s < NSEG; ++s) bt = fminf(bt, part[(size_t)s * NQ_TOT + q]);
    const int c = (int)(__float_as_uint(bt) & 0x7Fu);   // global 64-pt chunk

    const float* Q   = dir ? xyz2 : xyz1;
    const float* Rf  = dir ? xyz1 : xyz2;
    const float* NQp = dir ? nxyz2 : nxyz1;
    const float* NRp = dir ? nxyz1 : nxyz2;

    const size_t qoff = ((size_t)b * NPTS + i) * 3;
    const float x0 = Q[qoff], x1 = Q[qoff + 1], x2 = Q[qoff + 2];
    const float n0 = -x0, n1 = -x1, n2 = -x2;

    // re-scan winning chunk: exact argmin (strict <, ascending j)
    const float* Rs = Rf + ((size_t)b * NPTS + c * CHSZ) * 3;
    float btr = BIGF;
    int bj = 0;
    for (int j = 0; j < CHSZ; ++j) {
        float a = Rs[3 * j], cy = Rs[3 * j + 1], e = Rs[3 * j + 2];
        float h = 0.5f * fmaf(a, a, fmaf(cy, cy, e * e));
        float t = fmaf(n0, a, fmaf(n1, cy, fmaf(n2, e, h)));
        if (t < btr) { btr = t; bj = j; }
    }
    const int bi = c * CHSZ + bj;

    const size_t roff = ((size_t)b * NPTS + bi) * 3;
    const float y0 = Rf[roff], y1 = Rf[roff + 1], y2 = Rf[roff + 2];
    const float e0 = x0 - y0, e1 = x1 - y1, e2 = x2 - y2;
    float d = e0 * e0 + e1 * e1 + e2 * e2;      // exact squared distance

    const float a0 = NQp[qoff], a1 = NQp[qoff + 1], a2 = NQp[qoff + 2];
    const float c0 = NRp[roff], c1 = NRp[roff + 1], c2 = NRp[roff + 2];
    float na = sqrtf(a0 * a0 + a1 * a1 + a2 * a2);
    float nc = sqrtf(c0 * c0 + c1 * c1 + c2 * c2);
    float cs = (a0 * c0 + a1 * c1 + a2 * c2) /
               (fmaxf(na, CH_EPS) * fmaxf(nc, CH_EPS));
    float cn = 1.0f - fabsf(cs);

    for (int off = 32; off; off >>= 1) {
        d  += __shfl_down(d, off);
        cn += __shfl_down(cn, off);
    }
    const int lane = tid & 63, wv = tid >> 6;
    if (lane == 0) { red[0][wv] = d; red[1][wv] = cn; }
    __syncthreads();
    if (tid == 0) {
        float sd = red[0][0] + red[0][1] + red[0][2] + red[0][3];
        float sc = red[1][0] + red[1][1] + red[1][2] + red[1][3];
        const float inv = 1.0f / (float)(NB * NPTS);   // 1/32768
        atomicAdd(out + 0, sd * inv);
        atomicAdd(out + 1, sc * inv);
    }
}

extern "C" void kernel_launch(void* const* d_in, const int* in_sizes, int n_in,
                              void* d_out, int out_size, void* d_ws, size_t ws_size,
                              hipStream_t stream) {
    const float* xyz1  = (const float*)d_in[0];
    const float* xyz2  = (const float*)d_in[1];
    const float* nxyz1 = (const float*)d_in[2];
    const float* nxyz2 = (const float*)d_in[3];
    float* out = (float*)d_out;
    float* part = (float*)d_ws;                 // NSEG * 65536 * 4 B = 8 MB

    chamfer_partial<<<dim3(NPTS / QCHUNK, NSEG, 2 * NB), dim3(256), 0, stream>>>(
        xyz1, xyz2, part, out);
    finalize_kernel<<<dim3(NQ_TOT / 256), dim3(256), 0, stream>>>(
        xyz1, xyz2, nxyz1, nxyz2, part, out);
}

// Round 7
// 112.797 us; speedup vs baseline: 1.7261x; 1.0176x over previous
//
#include <hip/hip_runtime.h>

#define CH_EPS 1e-6f
#define NPTS 8192
#define NB 4
#define NSEG 64
#define SEGSZ (NPTS / NSEG)        // 128 refs per segment
#define CHSZ 32                    // points per argmin chunk
#define NCH (SEGSZ / CHSZ)         // 4 chunks per segment
#define QPT 16                     // queries per thread
#define QCHUNK (256 * QPT)         // 4096 queries per block
#define NQ_TOT (2 * NB * NPTS)     // 65536 queries (dir, batch, point)
#define BIGF 3.0e38f
#define CHMASK 0xFFFFFF00u         // clear low 8 bits: stuff global chunk id

// Order-preserving float->uint bijection (uint min == float min).
__device__ __forceinline__ unsigned mono(float f) {
    unsigned b = __float_as_uint(f);
    return (b & 0x80000000u) ? ~b : (b | 0x80000000u);
}
__device__ __forceinline__ unsigned mono_inv(unsigned u) {
    return (u & 0x80000000u) ? (u & 0x7FFFFFFFu) : ~u;
}

// Phase 1: per-(query, segment) chunked min scan.
// t = 0.5*|y|^2 - x.y has the same argmin as |x-y|^2 (y-dependent part).
// Hot loop: 3 FMA + 0.5 fmin per pair; once per 32-pt chunk the chunk min is
// folded (v_and_or_b32 + fmin) with its 8-bit global chunk id stuffed into
// the low mantissa bits. Cross-segment merge happens here too, via ONE
// device-scope atomicMin per (query, segment) on the monotone-mapped key --
// no big partial buffer, no merge loop in finalize, deterministic.
__global__ __launch_bounds__(256, 4) void chamfer_partial(
    const float* __restrict__ xyz1, const float* __restrict__ xyz2,
    unsigned* __restrict__ part, float* __restrict__ out) {
    __shared__ float4 sY[SEGSZ];                // 2 KB

    const int tid = threadIdx.x;
    const int chunk = blockIdx.x;               // 0..1 (4096-query chunks)
    const int seg = blockIdx.y;                 // 0..NSEG-1
    const int db = blockIdx.z;                  // 0..7
    const int dir = db >> 2, b = db & 3;

    // fold output zeroing into this kernel (finalize is a later dispatch)
    if (chunk == 0 && seg == 0 && db == 0 && tid < 2) out[tid] = 0.0f;

    const float* Q = dir ? xyz2 : xyz1;
    const float* R = (dir ? xyz1 : xyz2) + ((size_t)b * NPTS + seg * SEGSZ) * 3;

    // stage segment: (x, y, z, h = 0.5*|p|^2); h formula must match rescan
    if (tid < SEGSZ) {
        float a = R[3 * tid], c = R[3 * tid + 1], e = R[3 * tid + 2];
        sY[tid] = make_float4(a, c, e, 0.5f * fmaf(a, a, fmaf(c, c, e * e)));
    }

    float m0[QPT], m1[QPT], m2[QPT], bt[QPT];
    const int qi0 = chunk * QCHUNK + tid;
#pragma unroll
    for (int q = 0; q < QPT; ++q) {
        const size_t off = ((size_t)b * NPTS + qi0 + q * 256) * 3;
        m0[q] = -Q[off]; m1[q] = -Q[off + 1]; m2[q] = -Q[off + 2];
        bt[q] = BIGF;
    }
    __syncthreads();

    const unsigned gc0 = seg * NCH;             // global chunk id base (uniform)
#pragma unroll
    for (int cc = 0; cc < NCH; ++cc) {
        float cm[QPT];
#pragma unroll
        for (int q = 0; q < QPT; ++q) cm[q] = BIGF;
        const int jb = cc * CHSZ;
#pragma unroll 2
        for (int j = jb; j < jb + CHSZ; j += 4) {
            float4 y0 = sY[j];
            float4 y1 = sY[j + 1];
            float4 y2 = sY[j + 2];
            float4 y3 = sY[j + 3];
#pragma unroll
            for (int q = 0; q < QPT; ++q) {
                float t0 = fmaf(m0[q], y0.x, fmaf(m1[q], y0.y, fmaf(m2[q], y0.z, y0.w)));
                float t1 = fmaf(m0[q], y1.x, fmaf(m1[q], y1.y, fmaf(m2[q], y1.z, y1.w)));
                float t2 = fmaf(m0[q], y2.x, fmaf(m1[q], y2.y, fmaf(m2[q], y2.z, y2.w)));
                float t3 = fmaf(m0[q], y3.x, fmaf(m1[q], y3.y, fmaf(m2[q], y3.z, y3.w)));
                cm[q] = fminf(fminf(cm[q], t0), t1);   // -> v_min3_f32
                cm[q] = fminf(fminf(cm[q], t2), t3);   // -> v_min3_f32
            }
        }
        const unsigned gc = gc0 + cc;
#pragma unroll
        for (int q = 0; q < QPT; ++q) {
            // (bits & CHMASK) | gc  -> single v_and_or_b32
            float k = __uint_as_float((__float_as_uint(cm[q]) & CHMASK) | gc);
            bt[q] = fminf(bt[q], k);
        }
    }

    const int qbase = dir * (NB * NPTS) + b * NPTS + qi0;
#pragma unroll
    for (int q = 0; q < QPT; ++q)
        atomicMin(&part[qbase + q * 256], mono(bt[q]));
}

// Phase 2: one load per query (atomics already merged segments), decode the
// winning 32-point chunk, re-scan it exactly, distance + normal-consistency,
// block-reduce, atomicAdd.
__global__ __launch_bounds__(256) void finalize_kernel(
    const float* __restrict__ xyz1, const float* __restrict__ xyz2,
    const float* __restrict__ nxyz1, const float* __restrict__ nxyz2,
    const unsigned* __restrict__ part, float* __restrict__ out) {
    __shared__ float red[2][4];

    const int tid = threadIdx.x;
    const int q = blockIdx.x * 256 + tid;       // 0..65535
    const int dir = q >> 15;
    const int rem = q & 32767;
    const int b = rem >> 13;
    const int i = rem & 8191;

    const int c = (int)(mono_inv(part[q]) & 0xFFu);   // global 32-pt chunk

    const float* Q   = dir ? xyz2 : xyz1;
    const float* Rf  = dir ? xyz1 : xyz2;
    const float* NQp = dir ? nxyz2 : nxyz1;
    const float* NRp = dir ? nxyz1 : nxyz2;

    const size_t qoff = ((size_t)b * NPTS + i) * 3;
    const float x0 = Q[qoff], x1 = Q[qoff + 1], x2 = Q[qoff + 2];
    const float n0 = -x0, n1 = -x1, n2 = -x2;

    // re-scan winning chunk: exact argmin (strict <, ascending j)
    const float* Rs = Rf + ((size_t)b * NPTS + c * CHSZ) * 3;
    float btr = BIGF;
    int bj = 0;
    for (int j = 0; j < CHSZ; ++j) {
        float a = Rs[3 * j], cy = Rs[3 * j + 1], e = Rs[3 * j + 2];
        float h = 0.5f * fmaf(a, a, fmaf(cy, cy, e * e));
        float t = fmaf(n0, a, fmaf(n1, cy, fmaf(n2, e, h)));
        if (t < btr) { btr = t; bj = j; }
    }
    const int bi = c * CHSZ + bj;

    const size_t roff = ((size_t)b * NPTS + bi) * 3;
    const float y0 = Rf[roff], y1 = Rf[roff + 1], y2 = Rf[roff + 2];
    const float e0 = x0 - y0, e1 = x1 - y1, e2 = x2 - y2;
    float d = e0 * e0 + e1 * e1 + e2 * e2;      // exact squared distance

    const float a0 = NQp[qoff], a1 = NQp[qoff + 1], a2 = NQp[qoff + 2];
    const float c0 = NRp[roff], c1 = NRp[roff + 1], c2 = NRp[roff + 2];
    float na = sqrtf(a0 * a0 + a1 * a1 + a2 * a2);
    float nc = sqrtf(c0 * c0 + c1 * c1 + c2 * c2);
    float cs = (a0 * c0 + a1 * c1 + a2 * c2) /
               (fmaxf(na, CH_EPS) * fmaxf(nc, CH_EPS));
    float cn = 1.0f - fabsf(cs);

    for (int off = 32; off; off >>= 1) {
        d  += __shfl_down(d, off);
        cn += __shfl_down(cn, off);
    }
    const int lane = tid & 63, wv = tid >> 6;
    if (lane == 0) { red[0][wv] = d; red[1][wv] = cn; }
    __syncthreads();
    if (tid == 0) {
        float sd = red[0][0] + red[0][1] + red[0][2] + red[0][3];
        float sc = red[1][0] + red[1][1] + red[1][2] + red[1][3];
        const float inv = 1.0f / (float)(NB * NPTS);   // 1/32768
        atomicAdd(out + 0, sd * inv);
        atomicAdd(out + 1, sc * inv);
    }
}

extern "C" void kernel_launch(void* const* d_in, const int* in_sizes, int n_in,
                              void* d_out, int out_size, void* d_ws, size_t ws_size,
                              hipStream_t stream) {
    const float* xyz1  = (const float*)d_in[0];
    const float* xyz2  = (const float*)d_in[1];
    const float* nxyz1 = (const float*)d_in[2];
    const float* nxyz2 = (const float*)d_in[3];
    float* out = (float*)d_out;
    unsigned* part = (unsigned*)d_ws;           // 65536 * 4 B = 256 KB

    // init keys to +inf (all-ones = uint max)
    hipMemsetAsync(part, 0xFF, (size_t)NQ_TOT * sizeof(unsigned), stream);
    chamfer_partial<<<dim3(NPTS / QCHUNK, NSEG, 2 * NB), dim3(256), 0, stream>>>(
        xyz1, xyz2, part, out);
    finalize_kernel<<<dim3(NQ_TOT / 256), dim3(256), 0, stream>>>(
        xyz1, xyz2, nxyz1, nxyz2, part, out);
}